// Round 1
// baseline (2973.058 us; speedup 1.0000x reference)
//
#include <hip/hip_runtime.h>

#define BB 8
#define NN 8192
#define SS 1024
#define KK 32
#define NPIX (BB*SS*KK)   // 262144
#define R2C 0.04f
#define EPS 1e-5f

// ---------- ws layout (bytes) ----------
#define OFF_IDX      0u
#define OFF_NEWXYZ   (OFF_IDX + BB*SS*4)                    // (B,S) int32
#define OFF_GIDX     (OFF_NEWXYZ + BB*SS*3*4)               // (B,S,3) f32
#define OFF_XYZN     (OFF_GIDX + BB*SS*KK*4)                // (B,S,K) int32
#define OFF_PTSN     (OFF_XYZN + BB*NN*3*4)                 // (B,N,3) f32
#define OFF_Y0       (OFF_PTSN + BB*NN*64*4)                // (B,N,64) f32
#define OFF_Y1       (OFF_Y0 + NPIX*64*2)                   // bf16
#define OFF_MAXMIN   (OFF_Y1 + NPIX*64*2)                   // bf16
#define OFF_P0       (OFF_MAXMIN + BB*SS*128*2*4)
#define OFF_P1       (OFF_P0 + 1024*128*4)
#define OFF_P2       (OFF_P1 + 1024*128*4)
#define OFF_SC       (OFF_P2 + 1024*256*4)                  // scale0,shift0,scale1,shift1,scale2,shift2

__device__ __forceinline__ unsigned short f2bf(float x){
    unsigned u = __float_as_uint(x);
    unsigned r = (u + 0x7FFFu + ((u >> 16) & 1u)) >> 16;
    return (unsigned short)r;
}
__device__ __forceinline__ float bf2f(unsigned h){
    return __uint_as_float(h << 16);
}
__device__ __forceinline__ float sqdist3(float dx, float dy, float dz){
    // numpy order, no fma contraction: ((dx*dx)+(dy*dy))+(dz*dz)
    return __fadd_rn(__fadd_rn(__fmul_rn(dx,dx), __fmul_rn(dy,dy)), __fmul_rn(dz,dz));
}

// ---------- transpose: xyz (B,3,N)->(B,N,3), pts (B,64,N)->(B,N,64) ----------
__global__ __launch_bounds__(256) void t_kernel(const float* __restrict__ xyz,
                                                const float* __restrict__ pts,
                                                float* __restrict__ xyz_n,
                                                float* __restrict__ pts_n){
    int gid = blockIdx.x * 256 + threadIdx.x;   // 65536 = B*N
    int b = gid >> 13, i = gid & (NN - 1);
    const float* xb = xyz + (size_t)b * 3 * NN;
    float x = xb[i], y = xb[NN + i], z = xb[2 * NN + i];
    float* xd = xyz_n + ((size_t)b * NN + i) * 3;
    xd[0] = x; xd[1] = y; xd[2] = z;
    const float* pb = pts + (size_t)b * 64 * NN + i;
    float4* pd = (float4*)(pts_n + ((size_t)b * NN + i) * 64);
#pragma unroll
    for (int q = 0; q < 16; ++q){
        float4 v;
        v.x = pb[(q*4+0)*NN]; v.y = pb[(q*4+1)*NN];
        v.z = pb[(q*4+2)*NN]; v.w = pb[(q*4+3)*NN];
        pd[q] = v;
    }
}

// ---------- FPS: one block per batch ----------
__global__ __launch_bounds__(1024) void fps_kernel(const float* __restrict__ xyz,
                                                   int* __restrict__ idx,
                                                   float* __restrict__ newxyz,
                                                   float* __restrict__ out){
    __shared__ float sx[NN], sy[NN], sz[NN];
    __shared__ float rv[16];
    __shared__ int   ri[16];
    __shared__ int   s_last;
    int b = blockIdx.x, tid = threadIdx.x;
    float px[8], py[8], pz[8], dist[8];
    const float* xb = xyz + (size_t)b * 3 * NN;
#pragma unroll
    for (int j = 0; j < 8; ++j){
        int i = tid + j * 1024;
        float x = xb[i], y = xb[NN + i], z = xb[2 * NN + i];
        sx[i] = x; sy[i] = y; sz[i] = z;
        px[j] = x; py[j] = y; pz[j] = z;
        dist[j] = __int_as_float(0x7f800000); // +inf
    }
    if (tid == 0) s_last = 0;
    __syncthreads();
    for (int t = 0; t < SS; ++t){
        int last = s_last;
        float lx = sx[last], ly = sy[last], lz = sz[last];
        if (tid == 0){
            idx[b * SS + t] = last;
            out[(size_t)b * 3 * SS + t]           = lx;
            out[(size_t)b * 3 * SS + SS + t]      = ly;
            out[(size_t)b * 3 * SS + 2 * SS + t]  = lz;
            float* nw = newxyz + ((size_t)b * SS + t) * 3;
            nw[0] = lx; nw[1] = ly; nw[2] = lz;
        }
        float bestv = -1.f; int besti = 0;
#pragma unroll
        for (int j = 0; j < 8; ++j){
            float dx = __fsub_rn(px[j], lx);
            float dy = __fsub_rn(py[j], ly);
            float dz = __fsub_rn(pz[j], lz);
            float d = sqdist3(dx, dy, dz);
            float nd = fminf(dist[j], d);
            dist[j] = nd;
            int i = tid + j * 1024;
            if (nd > bestv){ bestv = nd; besti = i; }
        }
#pragma unroll
        for (int m = 1; m <= 32; m <<= 1){
            float ov = __shfl_xor(bestv, m);
            int   oi = __shfl_xor(besti, m);
            if (ov > bestv || (ov == bestv && oi < besti)){ bestv = ov; besti = oi; }
        }
        if ((tid & 63) == 0){ rv[tid >> 6] = bestv; ri[tid >> 6] = besti; }
        __syncthreads();
        if (tid < 64){
            float v = (tid < 16) ? rv[tid] : -2.f;
            int  ii = (tid < 16) ? ri[tid] : 0x7fffffff;
#pragma unroll
            for (int m = 1; m <= 8; m <<= 1){
                float ov = __shfl_xor(v, m);
                int   oi = __shfl_xor(ii, m);
                if (ov > v || (ov == v && oi < ii)){ v = ov; ii = oi; }
            }
            if (tid == 0) s_last = ii;
        }
        __syncthreads();
    }
}

// ---------- query ball: one wave per sample ----------
__global__ __launch_bounds__(256) void qb_kernel(const float* __restrict__ xyz_n,
                                                 const float* __restrict__ newxyz,
                                                 int* __restrict__ gidx){
    int wid = (blockIdx.x * 256 + threadIdx.x) >> 6;  // sample id 0..8191
    int lane = threadIdx.x & 63;
    int b = wid >> 10;
    const float* nw = newxyz + (size_t)wid * 3;
    float cx = nw[0], cy = nw[1], cz = nw[2];
    const float* xb = xyz_n + (size_t)b * NN * 3;
    int total = 0, firstIdx = -1;
    int* gout = gidx + (size_t)wid * KK;
    for (int base = 0; base < NN; base += 64){
        int i = base + lane;
        const float* p = xb + (size_t)i * 3;
        float dx = __fsub_rn(cx, p[0]);
        float dy = __fsub_rn(cy, p[1]);
        float dz = __fsub_rn(cz, p[2]);
        float d2 = sqdist3(dx, dy, dz);
        bool in = (d2 <= R2C);
        unsigned long long m = __ballot(in);
        int pos = total + __popcll(m & ((1ull << lane) - 1ull));
        if (in && pos < KK) gout[pos] = i;
        if (firstIdx < 0 && m) firstIdx = base + (__ffsll((unsigned long long)m) - 1);
        total += __popcll(m);
        if (total >= KK) break;
    }
    if (total < KK){
        int f = (total > 0) ? firstIdx : (NN - 1);
        for (int p = total + lane; p < KK; p += 64) gout[p] = f;
    }
}

// ---------- layer0: gather + 67->64 matmul + stats ----------
__global__ __launch_bounds__(256) void l0_kernel(const float* __restrict__ pts_n,
                                                 const float* __restrict__ xyz_n,
                                                 const float* __restrict__ newxyz,
                                                 const int* __restrict__ gidx,
                                                 const float* __restrict__ W0,
                                                 const float* __restrict__ b0,
                                                 uint4* __restrict__ y0,
                                                 float* __restrict__ part0){
    __shared__ float lsum[4][64][2];
    int tid = threadIdx.x;
    int pixel = blockIdx.x * 256 + tid;
    int sample = pixel >> 5;
    int b = sample >> 10;
    int gi = gidx[pixel];
    int wave = tid >> 6, lane = tid & 63;

    float ff[67];
    const float4* prow = (const float4*)(pts_n + ((size_t)b * NN + gi) * 64);
#pragma unroll
    for (int q = 0; q < 16; ++q){
        float4 v = prow[q];
        ff[q*4] = v.x; ff[q*4+1] = v.y; ff[q*4+2] = v.z; ff[q*4+3] = v.w;
    }
    const float* pr = xyz_n + ((size_t)b * NN + gi) * 3;
    const float* nw = newxyz + (size_t)sample * 3;
    ff[64] = __fsub_rn(pr[0], nw[0]) / 0.2f;
    ff[65] = __fsub_rn(pr[1], nw[1]) / 0.2f;
    ff[66] = __fsub_rn(pr[2], nw[2]) / 0.2f;

    for (int oc = 0; oc < 8; ++oc){
        float acc[8];
#pragma unroll
        for (int j = 0; j < 8; ++j) acc[j] = b0[oc*8+j];
#pragma unroll
        for (int c = 0; c < 67; ++c){
            float fe = ff[c];
#pragma unroll
            for (int j = 0; j < 8; ++j) acc[j] += fe * W0[(oc*8+j)*67 + c];
        }
        // stats + pack
        uint4 pk;
        unsigned us[8];
#pragma unroll
        for (int j = 0; j < 8; ++j){
            float v = acc[j];
            float s1 = v, s2 = v * v;
#pragma unroll
            for (int m = 1; m <= 32; m <<= 1){
                s1 += __shfl_xor(s1, m);
                s2 += __shfl_xor(s2, m);
            }
            if (lane == 0){ lsum[wave][oc*8+j][0] = s1; lsum[wave][oc*8+j][1] = s2; }
            us[j] = f2bf(v);
        }
        pk.x = us[0] | (us[1] << 16);
        pk.y = us[2] | (us[3] << 16);
        pk.z = us[4] | (us[5] << 16);
        pk.w = us[6] | (us[7] << 16);
        y0[(size_t)pixel * 8 + oc] = pk;
    }
    __syncthreads();
    if (tid < 128){
        float s = lsum[0][tid>>1][tid&1] + lsum[1][tid>>1][tid&1]
                + lsum[2][tid>>1][tid&1] + lsum[3][tid>>1][tid&1];
        part0[(size_t)blockIdx.x * 128 + tid] = s;
    }
}

// ---------- layer1: bn+relu + 64->64 matmul + stats ----------
__global__ __launch_bounds__(256) void l1_kernel(const uint4* __restrict__ y0,
                                                 const float* __restrict__ scale0,
                                                 const float* __restrict__ shift0,
                                                 const float* __restrict__ W1,
                                                 const float* __restrict__ b1,
                                                 uint4* __restrict__ y1,
                                                 float* __restrict__ part1){
    __shared__ float lsum[4][64][2];
    int tid = threadIdx.x;
    int pixel = blockIdx.x * 256 + tid;
    int wave = tid >> 6, lane = tid & 63;

    float x[64];
#pragma unroll
    for (int q = 0; q < 8; ++q){
        uint4 v = y0[(size_t)pixel * 8 + q];
        unsigned w[4] = {v.x, v.y, v.z, v.w};
#pragma unroll
        for (int r = 0; r < 4; ++r){
            int c = q*8 + r*2;
            x[c]   = fmaxf(bf2f(w[r] & 0xFFFFu) * scale0[c]   + shift0[c],   0.f);
            x[c+1] = fmaxf(bf2f(w[r] >> 16)     * scale0[c+1] + shift0[c+1], 0.f);
        }
    }
    for (int oc = 0; oc < 8; ++oc){
        float acc[8];
#pragma unroll
        for (int j = 0; j < 8; ++j) acc[j] = b1[oc*8+j];
#pragma unroll
        for (int c = 0; c < 64; ++c){
            float fe = x[c];
#pragma unroll
            for (int j = 0; j < 8; ++j) acc[j] += fe * W1[(oc*8+j)*64 + c];
        }
        uint4 pk;
        unsigned us[8];
#pragma unroll
        for (int j = 0; j < 8; ++j){
            float v = acc[j];
            float s1 = v, s2 = v * v;
#pragma unroll
            for (int m = 1; m <= 32; m <<= 1){
                s1 += __shfl_xor(s1, m);
                s2 += __shfl_xor(s2, m);
            }
            if (lane == 0){ lsum[wave][oc*8+j][0] = s1; lsum[wave][oc*8+j][1] = s2; }
            us[j] = f2bf(v);
        }
        pk.x = us[0] | (us[1] << 16);
        pk.y = us[2] | (us[3] << 16);
        pk.z = us[4] | (us[5] << 16);
        pk.w = us[6] | (us[7] << 16);
        y1[(size_t)pixel * 8 + oc] = pk;
    }
    __syncthreads();
    if (tid < 128){
        float s = lsum[0][tid>>1][tid&1] + lsum[1][tid>>1][tid&1]
                + lsum[2][tid>>1][tid&1] + lsum[3][tid>>1][tid&1];
        part1[(size_t)blockIdx.x * 128 + tid] = s;
    }
}

// ---------- layer2: bn+relu + 64->128 matmul + k-max/min + stats ----------
__global__ __launch_bounds__(256) void l2_kernel(const uint4* __restrict__ y1,
                                                 const float* __restrict__ scale1,
                                                 const float* __restrict__ shift1,
                                                 const float* __restrict__ W2,
                                                 const float* __restrict__ b2,
                                                 float* __restrict__ maxmin,
                                                 float* __restrict__ part2){
    __shared__ float lsum[4][128][2];
    int tid = threadIdx.x;
    int pixel = blockIdx.x * 256 + tid;
    int sample = pixel >> 5;
    int wave = tid >> 6, lane = tid & 63;

    float x[64];
#pragma unroll
    for (int q = 0; q < 8; ++q){
        uint4 v = y1[(size_t)pixel * 8 + q];
        unsigned w[4] = {v.x, v.y, v.z, v.w};
#pragma unroll
        for (int r = 0; r < 4; ++r){
            int c = q*8 + r*2;
            x[c]   = fmaxf(bf2f(w[r] & 0xFFFFu) * scale1[c]   + shift1[c],   0.f);
            x[c+1] = fmaxf(bf2f(w[r] >> 16)     * scale1[c+1] + shift1[c+1], 0.f);
        }
    }
    for (int oc = 0; oc < 16; ++oc){
        float acc[8];
#pragma unroll
        for (int j = 0; j < 8; ++j) acc[j] = b2[oc*8+j];
#pragma unroll
        for (int c = 0; c < 64; ++c){
            float fe = x[c];
#pragma unroll
            for (int j = 0; j < 8; ++j) acc[j] += fe * W2[(oc*8+j)*64 + c];
        }
#pragma unroll
        for (int j = 0; j < 8; ++j){
            float v = acc[j];
            int ch = oc*8 + j;
            float mx = v, mn = v;
#pragma unroll
            for (int m = 1; m <= 16; m <<= 1){
                mx = fmaxf(mx, __shfl_xor(mx, m));
                mn = fminf(mn, __shfl_xor(mn, m));
            }
            float s1 = v, s2 = v * v;
#pragma unroll
            for (int m = 1; m <= 32; m <<= 1){
                s1 += __shfl_xor(s1, m);
                s2 += __shfl_xor(s2, m);
            }
            if (lane == 0){ lsum[wave][ch][0] = s1; lsum[wave][ch][1] = s2; }
            if ((tid & 31) == 0){
                float* mm = maxmin + ((size_t)sample * 128 + ch) * 2;
                mm[0] = mx; mm[1] = mn;
            }
        }
    }
    __syncthreads();
    {
        float s = lsum[0][tid>>1][tid&1] + lsum[1][tid>>1][tid&1]
                + lsum[2][tid>>1][tid&1] + lsum[3][tid>>1][tid&1];
        part2[(size_t)blockIdx.x * 256 + tid] = s;
    }
}

// ---------- finalize BN params ----------
__global__ void fin_kernel(const float* __restrict__ part, int nblk, int O,
                           const float* __restrict__ g, const float* __restrict__ be,
                           float* __restrict__ scale, float* __restrict__ shift){
    int o = threadIdx.x;
    if (o >= O) return;
    float s1 = 0.f, s2 = 0.f;
    for (int blk = 0; blk < nblk; ++blk){
        s1 += part[(size_t)blk * 2 * O + o*2];
        s2 += part[(size_t)blk * 2 * O + o*2 + 1];
    }
    float inv = 1.0f / (float)NPIX;
    float mu = s1 * inv;
    float var = s2 * inv - mu * mu;
    float rs = 1.0f / sqrtf(var + EPS);
    float sc = rs * g[o];
    scale[o] = sc;
    shift[o] = be[o] - mu * sc;
}

// ---------- output: apply BN to max/min, relu, transpose write ----------
__global__ __launch_bounds__(256) void out_kernel(const float* __restrict__ maxmin,
                                                  const float* __restrict__ scale2,
                                                  const float* __restrict__ shift2,
                                                  float* __restrict__ out){
    int gid = blockIdx.x * 256 + threadIdx.x;  // 1048576, layout (b,o,s)
    int s = gid & 1023;
    int o = (gid >> 10) & 127;
    int b = gid >> 17;
    int sample = b * 1024 + s;
    float2 mm = ((const float2*)maxmin)[(size_t)sample * 128 + o];
    float sc = scale2[o], sh = shift2[o];
    float v = (sc >= 0.f) ? mm.x : mm.y;
    out[gid] = fmaxf(v * sc + sh, 0.f);
}

extern "C" void kernel_launch(void* const* d_in, const int* in_sizes, int n_in,
                              void* d_out, int out_size, void* d_ws, size_t ws_size,
                              hipStream_t stream) {
    const float* xyz = (const float*)d_in[0];
    const float* pts = (const float*)d_in[1];
    const float* W0 = (const float*)d_in[2];
    const float* b0 = (const float*)d_in[3];
    const float* g0 = (const float*)d_in[4];
    const float* be0 = (const float*)d_in[5];
    const float* W1 = (const float*)d_in[6];
    const float* b1 = (const float*)d_in[7];
    const float* g1 = (const float*)d_in[8];
    const float* be1 = (const float*)d_in[9];
    const float* W2 = (const float*)d_in[10];
    const float* b2 = (const float*)d_in[11];
    const float* g2 = (const float*)d_in[12];
    const float* be2 = (const float*)d_in[13];

    char* ws = (char*)d_ws;
    int*   idx    = (int*)(ws + OFF_IDX);
    float* newxyz = (float*)(ws + OFF_NEWXYZ);
    int*   gidx   = (int*)(ws + OFF_GIDX);
    float* xyz_n  = (float*)(ws + OFF_XYZN);
    float* pts_n  = (float*)(ws + OFF_PTSN);
    uint4* y0     = (uint4*)(ws + OFF_Y0);
    uint4* y1     = (uint4*)(ws + OFF_Y1);
    float* maxmin = (float*)(ws + OFF_MAXMIN);
    float* part0  = (float*)(ws + OFF_P0);
    float* part1  = (float*)(ws + OFF_P1);
    float* part2  = (float*)(ws + OFF_P2);
    float* sc     = (float*)(ws + OFF_SC);
    float* scale0 = sc,        *shift0 = sc + 64;
    float* scale1 = sc + 128,  *shift1 = sc + 192;
    float* scale2 = sc + 256,  *shift2 = sc + 384;

    float* out = (float*)d_out;
    float* out_np = out + BB * 3 * SS;

    hipLaunchKernelGGL(t_kernel, dim3(256), dim3(256), 0, stream, xyz, pts, xyz_n, pts_n);
    hipLaunchKernelGGL(fps_kernel, dim3(BB), dim3(1024), 0, stream, xyz, idx, newxyz, out);
    hipLaunchKernelGGL(qb_kernel, dim3(2048), dim3(256), 0, stream, xyz_n, newxyz, gidx);
    hipLaunchKernelGGL(l0_kernel, dim3(1024), dim3(256), 0, stream,
                       pts_n, xyz_n, newxyz, gidx, W0, b0, y0, part0);
    hipLaunchKernelGGL(fin_kernel, dim3(1), dim3(64), 0, stream, part0, 1024, 64, g0, be0, scale0, shift0);
    hipLaunchKernelGGL(l1_kernel, dim3(1024), dim3(256), 0, stream,
                       y0, scale0, shift0, W1, b1, y1, part1);
    hipLaunchKernelGGL(fin_kernel, dim3(1), dim3(64), 0, stream, part1, 1024, 64, g1, be1, scale1, shift1);
    hipLaunchKernelGGL(l2_kernel, dim3(1024), dim3(256), 0, stream,
                       y1, scale1, shift1, W2, b2, maxmin, part2);
    hipLaunchKernelGGL(fin_kernel, dim3(1), dim3(128), 0, stream, part2, 1024, 128, g2, be2, scale2, shift2);
    hipLaunchKernelGGL(out_kernel, dim3(4096), dim3(256), 0, stream, maxmin, scale2, shift2, out_np);
}

// Round 2
// 1765.607 us; speedup vs baseline: 1.6839x; 1.6839x over previous
//
#include <hip/hip_runtime.h>

#define BB 8
#define NN 8192
#define SS 1024
#define KK 32
#define NPIX (BB*SS*KK)   // 262144
#define R2C 0.04f
#define EPS 1e-5f

#define FT 512            // fps threads
#define FW (FT/64)        // 8 waves
#define PPT (NN/FT)       // 16 points per thread

// ---------- ws layout (bytes) ----------
#define OFF_IDX      0u
#define OFF_NEWXYZ   (OFF_IDX + BB*SS*4)                    // (B,S) int32 (unused now)
#define OFF_GIDX     (OFF_NEWXYZ + BB*SS*3*4)               // (B,S,3) f32
#define OFF_XYZN     (OFF_GIDX + BB*SS*KK*4)                // (B,S,K) int32
#define OFF_PTSN     (OFF_XYZN + BB*NN*3*4)                 // (B,N,3) f32
#define OFF_Y0       (OFF_PTSN + BB*NN*64*4)                // (B,N,64) f32
#define OFF_Y1       (OFF_Y0 + NPIX*64*2)                   // bf16
#define OFF_MAXMIN   (OFF_Y1 + NPIX*64*2)                   // bf16
#define OFF_P0       (OFF_MAXMIN + BB*SS*128*2*4)
#define OFF_P1       (OFF_P0 + 1024*128*4)
#define OFF_P2       (OFF_P1 + 1024*128*4)
#define OFF_SC       (OFF_P2 + 1024*256*4)                  // scale/shift x3

__device__ __forceinline__ unsigned short f2bf(float x){
    unsigned u = __float_as_uint(x);
    unsigned r = (u + 0x7FFFu + ((u >> 16) & 1u)) >> 16;
    return (unsigned short)r;
}
__device__ __forceinline__ float bf2f(unsigned h){
    return __uint_as_float(h << 16);
}
__device__ __forceinline__ float sqdist3(float dx, float dy, float dz){
    // numpy order, no fma contraction: ((dx*dx)+(dy*dy))+(dz*dz)
    return __fadd_rn(__fadd_rn(__fmul_rn(dx,dx), __fmul_rn(dy,dy)), __fmul_rn(dz,dz));
}

// ---------- transpose: xyz (B,3,N)->(B,N,3), pts (B,64,N)->(B,N,64) ----------
__global__ __launch_bounds__(256) void t_kernel(const float* __restrict__ xyz,
                                                const float* __restrict__ pts,
                                                float* __restrict__ xyz_n,
                                                float* __restrict__ pts_n){
    int gid = blockIdx.x * 256 + threadIdx.x;   // 65536 = B*N
    int b = gid >> 13, i = gid & (NN - 1);
    const float* xb = xyz + (size_t)b * 3 * NN;
    float x = xb[i], y = xb[NN + i], z = xb[2 * NN + i];
    float* xd = xyz_n + ((size_t)b * NN + i) * 3;
    xd[0] = x; xd[1] = y; xd[2] = z;
    const float* pb = pts + (size_t)b * 64 * NN + i;
    float4* pd = (float4*)(pts_n + ((size_t)b * NN + i) * 64);
#pragma unroll
    for (int q = 0; q < 16; ++q){
        float4 v;
        v.x = pb[(q*4+0)*NN]; v.y = pb[(q*4+1)*NN];
        v.z = pb[(q*4+2)*NN]; v.w = pb[(q*4+3)*NN];
        pd[q] = v;
    }
}

// ---------- FPS: one block per batch, ONE barrier per iteration ----------
__global__ __launch_bounds__(FT) void fps_kernel(const float* __restrict__ xyz,
                                                 float* __restrict__ newxyz,
                                                 float* __restrict__ out){
    __shared__ float sx[NN], sy[NN], sz[NN];
    __shared__ unsigned long long slots[2][FW];
    int b = blockIdx.x, tid = threadIdx.x;
    int wave = tid >> 6, lane = tid & 63;
    float px0[PPT/2], px1[PPT/2], py0[PPT/2], py1[PPT/2], pz0[PPT/2], pz1[PPT/2];
    float dist[PPT];
    const float* xb = xyz + (size_t)b * 3 * NN;
#pragma unroll
    for (int p = 0; p < PPT/2; ++p){
        int i0 = tid + (2*p) * FT, i1 = tid + (2*p+1) * FT;
        float x0 = xb[i0], y0 = xb[NN + i0], z0 = xb[2*NN + i0];
        float x1 = xb[i1], y1 = xb[NN + i1], z1 = xb[2*NN + i1];
        sx[i0] = x0; sy[i0] = y0; sz[i0] = z0;
        sx[i1] = x1; sy[i1] = y1; sz[i1] = z1;
        px0[p] = x0; px1[p] = x1; py0[p] = y0; py1[p] = y1; pz0[p] = z0; pz1[p] = z1;
        dist[2*p] = __int_as_float(0x7f800000);
        dist[2*p+1] = __int_as_float(0x7f800000);
    }
    __syncthreads();
    int winner = 0;
    for (int t = 0; t < SS; ++t){
        float lx = sx[winner], ly = sy[winner], lz = sz[winner];
        if (tid == 0){
            out[(size_t)b * 3 * SS + t]          = lx;
            out[(size_t)b * 3 * SS + SS + t]     = ly;
            out[(size_t)b * 3 * SS + 2*SS + t]   = lz;
            float* nw = newxyz + ((size_t)b * SS + t) * 3;
            nw[0] = lx; nw[1] = ly; nw[2] = lz;
        }
        float bestv = -1.f; int besti = 0;
        {
#pragma clang fp contract(off)
#pragma unroll
            for (int p = 0; p < PPT/2; ++p){
                // pairwise, SLP-friendly, strict IEEE per-op (numpy order)
                float dxa = px0[p] - lx, dxb = px1[p] - lx;
                float dya = py0[p] - ly, dyb = py1[p] - ly;
                float dza = pz0[p] - lz, dzb = pz1[p] - lz;
                float qxa = dxa*dxa, qxb = dxb*dxb;
                float qya = dya*dya, qyb = dyb*dyb;
                float qza = dza*dza, qzb = dzb*dzb;
                float sa = qxa + qya, sb = qxb + qyb;
                float da = sa + qza,  db = sb + qzb;
                float na = fminf(dist[2*p], da);
                float nb = fminf(dist[2*p+1], db);
                dist[2*p] = na; dist[2*p+1] = nb;
                int ia = tid + (2*p) * FT, ib = tid + (2*p+1) * FT;
                if (na > bestv){ bestv = na; besti = ia; }
                if (nb > bestv){ bestv = nb; besti = ib; }
            }
        }
        // packed key: max dist wins; tie -> smaller index (np.argmax semantics)
        unsigned long long key = ((unsigned long long)__float_as_uint(bestv) << 32)
                               | (unsigned)(~besti);
#pragma unroll
        for (int m = 1; m <= 32; m <<= 1){
            unsigned long long ok = __shfl_xor(key, m);
            key = (ok > key) ? ok : key;
        }
        if (lane == 0) slots[(t+1)&1][wave] = key;
        __syncthreads();
        unsigned long long k = slots[(t+1)&1][0];
#pragma unroll
        for (int w = 1; w < FW; ++w){
            unsigned long long ok = slots[(t+1)&1][w];
            k = (ok > k) ? ok : k;
        }
        winner = (int)(~(unsigned)k);
    }
}

// ---------- query ball: one wave per sample ----------
__global__ __launch_bounds__(256) void qb_kernel(const float* __restrict__ xyz_n,
                                                 const float* __restrict__ newxyz,
                                                 int* __restrict__ gidx){
    int wid = (blockIdx.x * 256 + threadIdx.x) >> 6;  // sample id 0..8191
    int lane = threadIdx.x & 63;
    int b = wid >> 10;
    const float* nw = newxyz + (size_t)wid * 3;
    float cx = nw[0], cy = nw[1], cz = nw[2];
    const float* xb = xyz_n + (size_t)b * NN * 3;
    int total = 0, firstIdx = -1;
    int* gout = gidx + (size_t)wid * KK;
    for (int base = 0; base < NN; base += 64){
        int i = base + lane;
        const float* p = xb + (size_t)i * 3;
        float dx = __fsub_rn(cx, p[0]);
        float dy = __fsub_rn(cy, p[1]);
        float dz = __fsub_rn(cz, p[2]);
        float d2 = sqdist3(dx, dy, dz);
        bool in = (d2 <= R2C);
        unsigned long long m = __ballot(in);
        int pos = total + __popcll(m & ((1ull << lane) - 1ull));
        if (in && pos < KK) gout[pos] = i;
        if (firstIdx < 0 && m) firstIdx = base + (__ffsll((unsigned long long)m) - 1);
        total += __popcll(m);
        if (total >= KK) break;
    }
    if (total < KK){
        int f = (total > 0) ? firstIdx : (NN - 1);
        for (int p = total + lane; p < KK; p += 64) gout[p] = f;
    }
}

// ---------- layer0: gather + 67->64 matmul + stats ----------
__global__ __launch_bounds__(256) void l0_kernel(const float* __restrict__ pts_n,
                                                 const float* __restrict__ xyz_n,
                                                 const float* __restrict__ newxyz,
                                                 const int* __restrict__ gidx,
                                                 const float* __restrict__ W0,
                                                 const float* __restrict__ b0,
                                                 uint4* __restrict__ y0,
                                                 float* __restrict__ part0){
    __shared__ float lsum[4][64][2];
    int tid = threadIdx.x;
    int pixel = blockIdx.x * 256 + tid;
    int sample = pixel >> 5;
    int b = sample >> 10;
    int gi = gidx[pixel];
    int wave = tid >> 6, lane = tid & 63;

    float ff[67];
    const float4* prow = (const float4*)(pts_n + ((size_t)b * NN + gi) * 64);
#pragma unroll
    for (int q = 0; q < 16; ++q){
        float4 v = prow[q];
        ff[q*4] = v.x; ff[q*4+1] = v.y; ff[q*4+2] = v.z; ff[q*4+3] = v.w;
    }
    const float* pr = xyz_n + ((size_t)b * NN + gi) * 3;
    const float* nw = newxyz + (size_t)sample * 3;
    ff[64] = __fsub_rn(pr[0], nw[0]) / 0.2f;
    ff[65] = __fsub_rn(pr[1], nw[1]) / 0.2f;
    ff[66] = __fsub_rn(pr[2], nw[2]) / 0.2f;

    for (int oc = 0; oc < 8; ++oc){
        float acc[8];
#pragma unroll
        for (int j = 0; j < 8; ++j) acc[j] = b0[oc*8+j];
#pragma unroll
        for (int c = 0; c < 67; ++c){
            float fe = ff[c];
#pragma unroll
            for (int j = 0; j < 8; ++j) acc[j] += fe * W0[(oc*8+j)*67 + c];
        }
        uint4 pk;
        unsigned us[8];
#pragma unroll
        for (int j = 0; j < 8; ++j){
            float v = acc[j];
            float s1 = v, s2 = v * v;
#pragma unroll
            for (int m = 1; m <= 32; m <<= 1){
                s1 += __shfl_xor(s1, m);
                s2 += __shfl_xor(s2, m);
            }
            if (lane == 0){ lsum[wave][oc*8+j][0] = s1; lsum[wave][oc*8+j][1] = s2; }
            us[j] = f2bf(v);
        }
        pk.x = us[0] | (us[1] << 16);
        pk.y = us[2] | (us[3] << 16);
        pk.z = us[4] | (us[5] << 16);
        pk.w = us[6] | (us[7] << 16);
        y0[(size_t)pixel * 8 + oc] = pk;
    }
    __syncthreads();
    if (tid < 128){
        float s = lsum[0][tid>>1][tid&1] + lsum[1][tid>>1][tid&1]
                + lsum[2][tid>>1][tid&1] + lsum[3][tid>>1][tid&1];
        part0[(size_t)blockIdx.x * 128 + tid] = s;
    }
}

// ---------- layer1: bn+relu + 64->64 matmul + stats ----------
__global__ __launch_bounds__(256) void l1_kernel(const uint4* __restrict__ y0,
                                                 const float* __restrict__ scale0,
                                                 const float* __restrict__ shift0,
                                                 const float* __restrict__ W1,
                                                 const float* __restrict__ b1,
                                                 uint4* __restrict__ y1,
                                                 float* __restrict__ part1){
    __shared__ float lsum[4][64][2];
    int tid = threadIdx.x;
    int pixel = blockIdx.x * 256 + tid;
    int wave = tid >> 6, lane = tid & 63;

    float x[64];
#pragma unroll
    for (int q = 0; q < 8; ++q){
        uint4 v = y0[(size_t)pixel * 8 + q];
        unsigned w[4] = {v.x, v.y, v.z, v.w};
#pragma unroll
        for (int r = 0; r < 4; ++r){
            int c = q*8 + r*2;
            x[c]   = fmaxf(bf2f(w[r] & 0xFFFFu) * scale0[c]   + shift0[c],   0.f);
            x[c+1] = fmaxf(bf2f(w[r] >> 16)     * scale0[c+1] + shift0[c+1], 0.f);
        }
    }
    for (int oc = 0; oc < 8; ++oc){
        float acc[8];
#pragma unroll
        for (int j = 0; j < 8; ++j) acc[j] = b1[oc*8+j];
#pragma unroll
        for (int c = 0; c < 64; ++c){
            float fe = x[c];
#pragma unroll
            for (int j = 0; j < 8; ++j) acc[j] += fe * W1[(oc*8+j)*64 + c];
        }
        uint4 pk;
        unsigned us[8];
#pragma unroll
        for (int j = 0; j < 8; ++j){
            float v = acc[j];
            float s1 = v, s2 = v * v;
#pragma unroll
            for (int m = 1; m <= 32; m <<= 1){
                s1 += __shfl_xor(s1, m);
                s2 += __shfl_xor(s2, m);
            }
            if (lane == 0){ lsum[wave][oc*8+j][0] = s1; lsum[wave][oc*8+j][1] = s2; }
            us[j] = f2bf(v);
        }
        pk.x = us[0] | (us[1] << 16);
        pk.y = us[2] | (us[3] << 16);
        pk.z = us[4] | (us[5] << 16);
        pk.w = us[6] | (us[7] << 16);
        y1[(size_t)pixel * 8 + oc] = pk;
    }
    __syncthreads();
    if (tid < 128){
        float s = lsum[0][tid>>1][tid&1] + lsum[1][tid>>1][tid&1]
                + lsum[2][tid>>1][tid&1] + lsum[3][tid>>1][tid&1];
        part1[(size_t)blockIdx.x * 128 + tid] = s;
    }
}

// ---------- layer2: bn+relu + 64->128 matmul + k-max/min + stats ----------
__global__ __launch_bounds__(256) void l2_kernel(const uint4* __restrict__ y1,
                                                 const float* __restrict__ scale1,
                                                 const float* __restrict__ shift1,
                                                 const float* __restrict__ W2,
                                                 const float* __restrict__ b2,
                                                 float* __restrict__ maxmin,
                                                 float* __restrict__ part2){
    __shared__ float lsum[4][128][2];
    int tid = threadIdx.x;
    int pixel = blockIdx.x * 256 + tid;
    int sample = pixel >> 5;
    int wave = tid >> 6, lane = tid & 63;

    float x[64];
#pragma unroll
    for (int q = 0; q < 8; ++q){
        uint4 v = y1[(size_t)pixel * 8 + q];
        unsigned w[4] = {v.x, v.y, v.z, v.w};
#pragma unroll
        for (int r = 0; r < 4; ++r){
            int c = q*8 + r*2;
            x[c]   = fmaxf(bf2f(w[r] & 0xFFFFu) * scale1[c]   + shift1[c],   0.f);
            x[c+1] = fmaxf(bf2f(w[r] >> 16)     * scale1[c+1] + shift1[c+1], 0.f);
        }
    }
    for (int oc = 0; oc < 16; ++oc){
        float acc[8];
#pragma unroll
        for (int j = 0; j < 8; ++j) acc[j] = b2[oc*8+j];
#pragma unroll
        for (int c = 0; c < 64; ++c){
            float fe = x[c];
#pragma unroll
            for (int j = 0; j < 8; ++j) acc[j] += fe * W2[(oc*8+j)*64 + c];
        }
#pragma unroll
        for (int j = 0; j < 8; ++j){
            float v = acc[j];
            int ch = oc*8 + j;
            float mx = v, mn = v;
#pragma unroll
            for (int m = 1; m <= 16; m <<= 1){
                mx = fmaxf(mx, __shfl_xor(mx, m));
                mn = fminf(mn, __shfl_xor(mn, m));
            }
            float s1 = v, s2 = v * v;
#pragma unroll
            for (int m = 1; m <= 32; m <<= 1){
                s1 += __shfl_xor(s1, m);
                s2 += __shfl_xor(s2, m);
            }
            if (lane == 0){ lsum[wave][ch][0] = s1; lsum[wave][ch][1] = s2; }
            if ((tid & 31) == 0){
                float* mm = maxmin + ((size_t)sample * 128 + ch) * 2;
                mm[0] = mx; mm[1] = mn;
            }
        }
    }
    __syncthreads();
    {
        float s = lsum[0][tid>>1][tid&1] + lsum[1][tid>>1][tid&1]
                + lsum[2][tid>>1][tid&1] + lsum[3][tid>>1][tid&1];
        part2[(size_t)blockIdx.x * 256 + tid] = s;
    }
}

// ---------- finalize BN params (parallel: 1024 threads) ----------
__global__ __launch_bounds__(1024) void fin_kernel(const float* __restrict__ part, int O,
                           const float* __restrict__ g, const float* __restrict__ be,
                           float* __restrict__ scale, float* __restrict__ shift){
    __shared__ float ls[1024];
    __shared__ float tot[256];
    int tid = threadIdx.x;
    int M = 2 * O;               // 128 or 256
    int C = 1024 / M;            // 8 or 4 chunks
    int m = tid & (M - 1);
    int chunk = tid / M;
    int per = 1024 / C;          // blocks per chunk
    float s = 0.f;
    for (int r = 0; r < per; ++r){
        int blk = chunk * per + r;
        s += part[(size_t)blk * M + m];
    }
    ls[tid] = s;
    __syncthreads();
    if (tid < M){
        float tt = 0.f;
        for (int c2 = 0; c2 < C; ++c2) tt += ls[c2 * M + tid];
        tot[tid] = tt;
    }
    __syncthreads();
    if (tid < O){
        float s1 = tot[2*tid], s2 = tot[2*tid+1];
        float inv = 1.0f / (float)NPIX;
        float mu = s1 * inv;
        float var = s2 * inv - mu * mu;
        float rs = 1.0f / sqrtf(var + EPS);
        float sc = rs * g[tid];
        scale[tid] = sc;
        shift[tid] = be[tid] - mu * sc;
    }
}

// ---------- output: apply BN to max/min, relu, transpose write ----------
__global__ __launch_bounds__(256) void out_kernel(const float* __restrict__ maxmin,
                                                  const float* __restrict__ scale2,
                                                  const float* __restrict__ shift2,
                                                  float* __restrict__ out){
    int gid = blockIdx.x * 256 + threadIdx.x;  // 1048576, layout (b,o,s)
    int s = gid & 1023;
    int o = (gid >> 10) & 127;
    int b = gid >> 17;
    int sample = b * 1024 + s;
    float2 mm = ((const float2*)maxmin)[(size_t)sample * 128 + o];
    float sc = scale2[o], sh = shift2[o];
    float v = (sc >= 0.f) ? mm.x : mm.y;
    out[gid] = fmaxf(v * sc + sh, 0.f);
}

extern "C" void kernel_launch(void* const* d_in, const int* in_sizes, int n_in,
                              void* d_out, int out_size, void* d_ws, size_t ws_size,
                              hipStream_t stream) {
    const float* xyz = (const float*)d_in[0];
    const float* pts = (const float*)d_in[1];
    const float* W0 = (const float*)d_in[2];
    const float* b0 = (const float*)d_in[3];
    const float* g0 = (const float*)d_in[4];
    const float* be0 = (const float*)d_in[5];
    const float* W1 = (const float*)d_in[6];
    const float* b1 = (const float*)d_in[7];
    const float* g1 = (const float*)d_in[8];
    const float* be1 = (const float*)d_in[9];
    const float* W2 = (const float*)d_in[10];
    const float* b2 = (const float*)d_in[11];
    const float* g2 = (const float*)d_in[12];
    const float* be2 = (const float*)d_in[13];

    char* ws = (char*)d_ws;
    float* newxyz = (float*)(ws + OFF_NEWXYZ);
    int*   gidx   = (int*)(ws + OFF_GIDX);
    float* xyz_n  = (float*)(ws + OFF_XYZN);
    float* pts_n  = (float*)(ws + OFF_PTSN);
    uint4* y0     = (uint4*)(ws + OFF_Y0);
    uint4* y1     = (uint4*)(ws + OFF_Y1);
    float* maxmin = (float*)(ws + OFF_MAXMIN);
    float* part0  = (float*)(ws + OFF_P0);
    float* part1  = (float*)(ws + OFF_P1);
    float* part2  = (float*)(ws + OFF_P2);
    float* sc     = (float*)(ws + OFF_SC);
    float* scale0 = sc,        *shift0 = sc + 64;
    float* scale1 = sc + 128,  *shift1 = sc + 192;
    float* scale2 = sc + 256,  *shift2 = sc + 384;

    float* out = (float*)d_out;
    float* out_np = out + BB * 3 * SS;

    hipLaunchKernelGGL(t_kernel, dim3(256), dim3(256), 0, stream, xyz, pts, xyz_n, pts_n);
    hipLaunchKernelGGL(fps_kernel, dim3(BB), dim3(FT), 0, stream, xyz, newxyz, out);
    hipLaunchKernelGGL(qb_kernel, dim3(2048), dim3(256), 0, stream, xyz_n, newxyz, gidx);
    hipLaunchKernelGGL(l0_kernel, dim3(1024), dim3(256), 0, stream,
                       pts_n, xyz_n, newxyz, gidx, W0, b0, y0, part0);
    hipLaunchKernelGGL(fin_kernel, dim3(1), dim3(1024), 0, stream, part0, 64, g0, be0, scale0, shift0);
    hipLaunchKernelGGL(l1_kernel, dim3(1024), dim3(256), 0, stream,
                       y0, scale0, shift0, W1, b1, y1, part1);
    hipLaunchKernelGGL(fin_kernel, dim3(1), dim3(1024), 0, stream, part1, 64, g1, be1, scale1, shift1);
    hipLaunchKernelGGL(l2_kernel, dim3(1024), dim3(256), 0, stream,
                       y1, scale1, shift1, W2, b2, maxmin, part2);
    hipLaunchKernelGGL(fin_kernel, dim3(1), dim3(1024), 0, stream, part2, 128, g2, be2, scale2, shift2);
    hipLaunchKernelGGL(out_kernel, dim3(4096), dim3(256), 0, stream, maxmin, scale2, shift2, out_np);
}